// Round 1
// baseline (1969.122 us; speedup 1.0000x reference)
//
#include <hip/hip_runtime.h>

#define NN 256
#define CIN 96
#define COUT 96
#define BB 4

__device__ __forceinline__ float waveReduceSum(float v) {
    #pragma unroll
    for (int m = 32; m >= 1; m >>= 1) v += __shfl_xor(v, m, 64);
    return v;
}

// ---------------- K1: per (b,c) rowsum / colsum / diag / T / S ----------------
__global__ __launch_bounds__(256) void k_aux(const float* __restrict__ X,
                                             float* __restrict__ rows,
                                             float* __restrict__ cols,
                                             float* __restrict__ diag,
                                             float* __restrict__ TSa) {
    const int bc = blockIdx.x;                 // 0..B*C-1
    const float* Xp = X + (size_t)bc * NN * NN;
    const int tid = threadIdx.x;
    const int wave = tid >> 6, lane = tid & 63;

    __shared__ float rowsL[NN];
    __shared__ float colPart[4][NN];
    __shared__ float sred[8];

    float4 csum = make_float4(0.f, 0.f, 0.f, 0.f);
    for (int p = wave; p < NN; p += 4) {
        float4 v = *(const float4*)(Xp + (size_t)p * NN + lane * 4);
        csum.x += v.x; csum.y += v.y; csum.z += v.z; csum.w += v.w;
        float rs = waveReduceSum(v.x + v.y + v.z + v.w);
        if (lane == 0) rowsL[p] = rs;
    }
    *(float4*)(&colPart[wave][lane * 4]) = csum;
    __syncthreads();

    float col = colPart[0][tid] + colPart[1][tid] + colPart[2][tid] + colPart[3][tid];
    const size_t gb = (size_t)bc * NN;
    cols[gb + tid] = col;
    float rsv = rowsL[tid];
    rows[gb + tid] = rsv;
    float d = Xp[(size_t)tid * (NN + 1)];
    diag[gb + tid] = d;

    float t1 = waveReduceSum(d);
    float s1 = waveReduceSum(rsv);
    if (lane == 0) { sred[wave] = t1; sred[4 + wave] = s1; }
    __syncthreads();
    if (tid == 0) {
        TSa[bc * 2 + 0] = sred[0] + sred[1] + sred[2] + sred[3];
        TSa[bc * 2 + 1] = sred[4] + sred[5] + sred[6] + sred[7];
    }
}

// ---------------- K2: P' / Q / G' per (b,o,p) ----------------
__global__ __launch_bounds__(256) void k_pqg(const float* __restrict__ W,   // 15*CIN*COUT
                                             const float* __restrict__ rows,
                                             const float* __restrict__ cols,
                                             const float* __restrict__ diag,
                                             const float* __restrict__ TSa,
                                             const float* __restrict__ bias,
                                             float* __restrict__ Pw,
                                             float* __restrict__ Qw,
                                             float* __restrict__ Gw) {
    const int bo = blockIdx.x;      // b*COUT + o
    const int b = bo / COUT, o = bo % COUT;
    const int p = threadIdx.x;

    float P = 0.f, Q = 0.f, G = 0.f, s = 0.f, gs = 0.f;
    for (int c = 0; c < CIN; ++c) {
        const size_t base = (size_t)(b * CIN + c) * NN;
        float r  = rows[base + p];
        float cl = cols[base + p];
        float dg = diag[base + p];
        const float* wp = W + c * COUT + o;
        #define WI(i) wp[(i) * CIN * COUT]
        P += WI(12) * r + WI(7)  * cl + WI(5) * dg;
        Q += WI(13) * r + WI(10) * cl + WI(9) * dg;
        G += WI(3)  * r + WI(1)  * cl + WI(0) * dg;
        float Tv = TSa[(b * CIN + c) * 2 + 0];
        float Sv = TSa[(b * CIN + c) * 2 + 1];
        s  += WI(11) * Tv + WI(14) * Sv;
        gs += WI(2)  * Tv + WI(4)  * Sv;
        #undef WI
    }
    const size_t ob = (size_t)bo * NN;
    Pw[ob + p] = P + s + bias[0];
    Qw[ob + p] = Q;
    Gw[ob + p] = G + gs;
}

// ---------------- K3: main channel-mix ----------------
// Y[b,o,p,q] = sum_c w8[c,o]*X[b,c,p,q] + sum_c w6[c,o]*X[b,c,q,p]
//            + Pw[b,o,p] + Qw[b,o,q] + (p==q)*Gw[b,o,p]
#define BK 8
__global__ __launch_bounds__(256, 2) void k_main(const float* __restrict__ X,
                                                 const float* __restrict__ W,
                                                 const float* __restrict__ Pw,
                                                 const float* __restrict__ Qw,
                                                 const float* __restrict__ Gw,
                                                 float* __restrict__ Y) {
    const int tq = blockIdx.x, tp = blockIdx.y, b = blockIdx.z;
    const int tid = threadIdx.x;
    const int to = tid >> 4, ts = tid & 15;   // o-group (6 each), pixel-row in tile

    __shared__ float XA [BK][16][20];   // direct tile, padded stride 20 (80B, f4-aligned)
    __shared__ float XBt[BK][16][20];   // transposed tile
    __shared__ float W8s[BK * 96];
    __shared__ float W6s[BK * 96];

    float acc[6][16];
    #pragma unroll
    for (int j = 0; j < 6; ++j)
        #pragma unroll
        for (int e = 0; e < 16; ++e) acc[j][e] = 0.f;

    const float* w8g = W + 8 * CIN * COUT;
    const float* w6g = W + 6 * CIN * COUT;
    const float* Xb = X + (size_t)b * CIN * NN * NN;

    for (int c0 = 0; c0 < CIN; c0 += BK) {
        // ---- stage X tiles + weight chunks ----
        #pragma unroll
        for (int i = 0; i < 2; ++i) {
            int g = tid + 256 * i;            // 0..511 float4-units
            int cc = g >> 6, r = g & 63;
            int pp = r >> 2, jv = r & 3;
            const float* pa = Xb + ((size_t)(c0 + cc) * NN + (tp * 16 + pp)) * NN + tq * 16 + jv * 4;
            float4 va = *(const float4*)pa;
            *(float4*)&XA[cc][pp][jv * 4] = va;
            const float* pb = Xb + ((size_t)(c0 + cc) * NN + (tq * 16 + pp)) * NN + tp * 16 + jv * 4;
            float4 vb = *(const float4*)pb;
            XBt[cc][jv * 4 + 0][pp] = vb.x;
            XBt[cc][jv * 4 + 1][pp] = vb.y;
            XBt[cc][jv * 4 + 2][pp] = vb.z;
            XBt[cc][jv * 4 + 3][pp] = vb.w;
        }
        #pragma unroll
        for (int j = 0; j < 3; ++j) {
            int idx = tid + 256 * j;          // 0..767 == c'*96 + o
            W8s[idx] = w8g[c0 * 96 + idx];
            W6s[idx] = w6g[c0 * 96 + idx];
        }
        __syncthreads();

        // ---- compute ----
        #pragma unroll
        for (int cc = 0; cc < BK; ++cc) {
            float xd[16], xt[16];
            const float4* xa = (const float4*)&XA[cc][ts][0];
            const float4* xb = (const float4*)&XBt[cc][ts][0];
            #pragma unroll
            for (int u = 0; u < 4; ++u) {
                ((float4*)xd)[u] = xa[u];
                ((float4*)xt)[u] = xb[u];
            }
            #pragma unroll
            for (int j = 0; j < 6; ++j) {
                float a8 = W8s[cc * 96 + to * 6 + j];
                float a6 = W6s[cc * 96 + to * 6 + j];
                #pragma unroll
                for (int e = 0; e < 16; ++e)
                    acc[j][e] += a8 * xd[e] + a6 * xt[e];
            }
        }
        __syncthreads();
    }

    // ---- epilogue ----
    const int p = tp * 16 + ts;
    #pragma unroll
    for (int j = 0; j < 6; ++j) {
        const int o = to * 6 + j;
        const size_t ob = (size_t)(b * COUT + o) * NN;
        float Pv = Pw[ob + p];
        float Gv = Gw[ob + p];
        float qv[16];
        const float4* qp = (const float4*)&Qw[ob + tq * 16];
        #pragma unroll
        for (int u = 0; u < 4; ++u) ((float4*)qv)[u] = qp[u];
        float out[16];
        #pragma unroll
        for (int e = 0; e < 16; ++e) {
            float v = acc[j][e] + Pv + qv[e];
            if (tp == tq && e == ts) v += Gv;
            out[e] = v;
        }
        float* yp = Y + (ob + p) * NN + tq * 16;
        #pragma unroll
        for (int u = 0; u < 4; ++u) ((float4*)yp)[u] = ((float4*)out)[u];
    }
}

extern "C" void kernel_launch(void* const* d_in, const int* in_sizes, int n_in,
                              void* d_out, int out_size, void* d_ws, size_t ws_size,
                              hipStream_t stream) {
    const float* X    = (const float*)d_in[0];
    // d_in[1] (Y_in) is unused by the reference
    const float* W    = (const float*)d_in[2];   // [15][96][96]
    const float* bias = (const float*)d_in[3];
    float* Y = (float*)d_out;

    float* ws   = (float*)d_ws;
    const size_t SEG = (size_t)BB * CIN * NN;    // 98304 (same for B*COUT*NN)
    float* rows = ws;
    float* cols = ws + SEG;
    float* diag = ws + 2 * SEG;
    float* Pw   = ws + 3 * SEG;
    float* Qw   = ws + 4 * SEG;
    float* Gw   = ws + 5 * SEG;
    float* TSa  = ws + 6 * SEG;                  // B*CIN*2 floats

    k_aux<<<BB * CIN, 256, 0, stream>>>(X, rows, cols, diag, TSa);
    k_pqg<<<BB * COUT, 256, 0, stream>>>(W, rows, cols, diag, TSa, bias, Pw, Qw, Gw);
    k_main<<<dim3(NN / 16, NN / 16, BB), 256, 0, stream>>>(X, W, Pw, Qw, Gw, Y);
}